// Round 1
// baseline (46.640 us; speedup 1.0000x reference)
//
#include <hip/hip_runtime.h>

// NTfm3D: out[b,i,h,w] = sum_k masks[b,k,h,w] * (R[b,k,i,:] . points[b,:,h,w] + t[b,k,i])
// Shapes: points (B,3,H,W) f32, masks (B,K,H,W) f32, transforms (B,K,3,4) f32
// B=16, K=8, H=480, W=640. Memory-bound: 56 B/pixel, ~276 MB total.

constexpr int B_ = 16;
constexpr int K_ = 8;
constexpr int H_ = 480;
constexpr int W_ = 640;
constexpr int HW_ = H_ * W_;          // 307200, divisible by 4
constexpr int VEC = 4;
constexpr int BLOCK = 256;
constexpr int PIX_PER_BLOCK = BLOCK * VEC;   // 1024
constexpr int BLOCKS_PER_B = HW_ / PIX_PER_BLOCK;  // 300

__global__ __launch_bounds__(BLOCK) void ntfm3d_kernel(
    const float* __restrict__ points,      // (B,3,H,W)
    const float* __restrict__ masks,       // (B,K,H,W)
    const float* __restrict__ transforms,  // (B,K,3,4)
    float* __restrict__ out)               // (B,3,H,W)
{
    __shared__ float tf[K_ * 12];  // [k][i][j], j=0..2 -> R, j=3 -> t

    const int b = blockIdx.y;

    // Stage this batch's 8 transforms (96 floats) into LDS once.
    if (threadIdx.x < K_ * 12) {
        tf[threadIdx.x] = transforms[(size_t)b * K_ * 12 + threadIdx.x];
    }
    __syncthreads();

    const int p = (blockIdx.x * BLOCK + threadIdx.x) * VEC;  // pixel index in plane

    const float* pp = points + (size_t)b * 3 * HW_ + p;
    const float4 x = *reinterpret_cast<const float4*>(pp);
    const float4 y = *reinterpret_cast<const float4*>(pp + HW_);
    const float4 z = *reinterpret_cast<const float4*>(pp + 2 * HW_);

    float4 acc0 = {0.f, 0.f, 0.f, 0.f};
    float4 acc1 = {0.f, 0.f, 0.f, 0.f};
    float4 acc2 = {0.f, 0.f, 0.f, 0.f};

    const float* mp = masks + (size_t)b * K_ * HW_ + p;

#pragma unroll
    for (int k = 0; k < K_; ++k) {
        const float4 m = *reinterpret_cast<const float4*>(mp + (size_t)k * HW_);
        const float* T = tf + k * 12;
        const float r00 = T[0], r01 = T[1], r02 = T[2],  t0 = T[3];
        const float r10 = T[4], r11 = T[5], r12 = T[6],  t1 = T[7];
        const float r20 = T[8], r21 = T[9], r22 = T[10], t2 = T[11];

#define APPLY(c)                                                             \
        {                                                                    \
            float s0 = fmaf(r00, x.c, fmaf(r01, y.c, fmaf(r02, z.c, t0)));   \
            float s1 = fmaf(r10, x.c, fmaf(r11, y.c, fmaf(r12, z.c, t1)));   \
            float s2 = fmaf(r20, x.c, fmaf(r21, y.c, fmaf(r22, z.c, t2)));   \
            acc0.c = fmaf(m.c, s0, acc0.c);                                  \
            acc1.c = fmaf(m.c, s1, acc1.c);                                  \
            acc2.c = fmaf(m.c, s2, acc2.c);                                  \
        }
        APPLY(x) APPLY(y) APPLY(z) APPLY(w)
#undef APPLY
    }

    float* op = out + (size_t)b * 3 * HW_ + p;
    *reinterpret_cast<float4*>(op)          = acc0;
    *reinterpret_cast<float4*>(op + HW_)    = acc1;
    *reinterpret_cast<float4*>(op + 2*HW_)  = acc2;
}

extern "C" void kernel_launch(void* const* d_in, const int* in_sizes, int n_in,
                              void* d_out, int out_size, void* d_ws, size_t ws_size,
                              hipStream_t stream) {
    const float* points     = (const float*)d_in[0];
    const float* masks      = (const float*)d_in[1];
    const float* transforms = (const float*)d_in[2];
    float* out              = (float*)d_out;

    dim3 grid(BLOCKS_PER_B, B_);
    dim3 block(BLOCK);
    ntfm3d_kernel<<<grid, block, 0, stream>>>(points, masks, transforms, out);
}